// Round 5
// baseline (320.591 us; speedup 1.0000x reference)
//
#include <hip/hip_runtime.h>

typedef unsigned short u16;
typedef __attribute__((ext_vector_type(4))) float f32x4;
typedef __attribute__((ext_vector_type(8))) __bf16 bf16x8;
typedef __attribute__((ext_vector_type(8))) short short8;
typedef __attribute__((ext_vector_type(4))) u16 u16x4;

__device__ __forceinline__ u16 f2bf(float f) {
    union { float f; unsigned u; } v; v.f = f;
    unsigned r = v.u + 0x7fffu + ((v.u >> 16) & 1u);
    return (u16)(r >> 16);
}

__device__ __forceinline__ f32x4 mfma16(bf16x8 a, bf16x8 b, f32x4 c) {
    return __builtin_amdgcn_mfma_f32_16x16x32_bf16(a, b, c, 0, 0, 0);
}

__device__ __forceinline__ void gload16(const u16* g, u16* lds) {
    __builtin_amdgcn_global_load_lds(
        (const __attribute__((address_space(1))) void*)g,
        (__attribute__((address_space(3))) void*)lds, 16, 0, 0);
}

// ---------------- f32 -> bf16 conversion ----------------
__global__ void cvt_bf16_kernel(const float* __restrict__ src, u16* __restrict__ dst, int n4) {
    int i = blockIdx.x * blockDim.x + threadIdx.x;
    if (i >= n4) return;
    float4 v = ((const float4*)src)[i];
    u16x4 o = { f2bf(v.x), f2bf(v.y), f2bf(v.z), f2bf(v.w) };
    *(u16x4*)&dst[i * 4] = o;
}

// ---------------- RoPE cos/sin table [2048][32] ----------------
__global__ void rope_tbl_kernel(const int* __restrict__ pos, float2* __restrict__ tbl) {
    int i = blockIdx.x * blockDim.x + threadIdx.x;   // 65536
    int s = i >> 5, p = i & 31;
    float inv = powf(10000.0f, -(float)p / 32.0f);
    float a = (float)pos[s] * inv;
    float sn, cs;
    sincosf(a, &sn, &cs);
    tbl[i] = make_float2(cs, sn);
}

// ---------------- GEMM C = A @ B^T  (m97 structure, 128x128 tile, BK=32) ------
// MODE 0: C[row][N] f32 output.
// MODE 1: QKV epilogue: RoPE + split into
//   Q[bh][s][64]  (pre-scaled by 1/8*log2e, attn works in exp2 domain)
//   Kswz[bh][s][d ^ ((s&7)<<3)]                     (XOR-swizzled for LDS)
//   Vp[bh][d][tile][p ^ ((d&7)<<3)] where p encodes the MFMA k-slot order:
//     p = 32*(r>>5) + 8*((r>>2)&3) + 4*((r>>4)&1) + (r&3),  r = kv & 63
template<int MODE>
__global__ __launch_bounds__(256) void gemm_bt(
    const u16* __restrict__ A, const u16* __restrict__ B,
    float* __restrict__ C, int N,
    u16* __restrict__ Qt, u16* __restrict__ Ktn, u16* __restrict__ VTt,
    const float2* __restrict__ tbl)
{
    __shared__ alignas(16) u16 As[128 * 32];
    __shared__ alignas(16) u16 Bs[128 * 32];
    const int t = threadIdx.x;
    const int l = t & 63, w = t >> 6;
    const int lg = l >> 4, lc = l & 15;
    const int wr = w >> 1, wc = w & 1;
    const int brow = blockIdx.y * 128, bcol = blockIdx.x * 128;
    const int sr = w * 16 + (l >> 2), sc = (l & 3) * 8;
    const u16* ga = A + (size_t)(brow + sr) * 1024 + sc;
    const u16* gb = B + (size_t)(bcol + sr) * 1024 + sc;
    u16* la = &As[w * 512];
    u16* lb = &Bs[w * 512];
    f32x4 acc[4][4] = {};

    for (int kt = 0; kt < 1024; kt += 32) {
        __syncthreads();
        gload16(ga + kt, la);
        gload16(ga + 64 * 1024 + kt, la + 2048);
        gload16(gb + kt, lb);
        gload16(gb + 64 * 1024 + kt, lb + 2048);
        __syncthreads();
        bf16x8 af[4], bfr[4];
#pragma unroll
        for (int i = 0; i < 4; ++i)
            af[i] = *(const bf16x8*)&As[(wr * 64 + i * 16 + lc) * 32 + lg * 8];
#pragma unroll
        for (int j = 0; j < 4; ++j)
            bfr[j] = *(const bf16x8*)&Bs[(wc * 64 + j * 16 + lc) * 32 + lg * 8];
#pragma unroll
        for (int i = 0; i < 4; ++i)
#pragma unroll
            for (int j = 0; j < 4; ++j)
                acc[i][j] = mfma16(af[i], bfr[j], acc[i][j]);
    }

    if (MODE == 0) {
#pragma unroll
        for (int i = 0; i < 4; ++i) {
            int row = brow + wr * 64 + i * 16 + lg * 4;
#pragma unroll
            for (int j = 0; j < 4; ++j) {
                int col = bcol + wc * 64 + j * 16 + lc;
#pragma unroll
                for (int jj = 0; jj < 4; ++jj)
                    C[(size_t)(row + jj) * N + col] = acc[i][j][jj];
            }
        }
    } else {
        const int b = brow >> 11;
#pragma unroll
        for (int i = 0; i < 4; ++i) {
            int s0 = (brow & 2047) + wr * 64 + i * 16 + lg * 4;
#pragma unroll
            for (int j = 0; j < 4; ++j) {
                int e0 = bcol + wc * 64 + j * 16;     // wave-uniform
                int region = e0 >> 10;                // 0=q 1=k 2=v
                int er = e0 & 1023;
                int h = er >> 6;                      // wave-uniform
                int d = (er & 63) + lc;               // per-lane
                size_t bh = (size_t)(b * 16 + h);
                if (region <= 1) {
                    int p = d >> 1;
                    float sgn = (d & 1) ? 1.0f : -1.0f;   // even: -sin, odd: +sin
                    u16* dst = (region == 0) ? Qt : Ktn;
                    float mul = (region == 0) ? 0.18033688011112043f : 1.0f;
#pragma unroll
                    for (int jj = 0; jj < 4; ++jj) {
                        float v = acc[i][j][jj];
                        float pr = __shfl_xor(v, 1);
                        float2 cs = tbl[(size_t)(s0 + jj) * 32 + p];
                        float o = (v * cs.x + pr * cs.y * sgn) * mul;
                        int s = s0 + jj;
                        int dd = (region == 0) ? d : (d ^ ((s & 7) << 3));
                        dst[((size_t)bh * 2048 + s) * 64 + dd] = f2bf(o);
                    }
                } else {
                    // V: permuted + swizzled layout for direct b128 PV A-frag reads
                    int tile = s0 >> 6, r = s0 & 63;
                    int p0 = ((r >> 5) << 5) + (((r >> 2) & 3) << 3) + (((r >> 4) & 1) << 2);
                    int idx = (tile << 6) + (p0 ^ ((d & 7) << 3));
                    u16x4 pk;
#pragma unroll
                    for (int jj = 0; jj < 4; ++jj) pk[jj] = f2bf(acc[i][j][jj]);
                    *(u16x4*)&VTt[((size_t)bh * 64 + d) * 2048 + idx] = pk;
                }
            }
        }
    }
}

// ---------------- causal flash attention (swapped-operand) --------------------
// grid: 2048 blocks = 32 q-tiles (heavy first) x 64 bh; 128 threads = 2 waves.
// Wave handles 32 q (2 frags of 16); KVBLK=64; K/V staged via global_load_lds
// from pre-swizzled ws layouts; all LDS reads single conflict-free b128.
// S^T = mfma(K,Q): lane(lg,lc) elem jj -> k=kv0+nb*16+4lg+jj, q=qb0+16f+lc.
// NOTE: a q-row's 64 k-values are spread across the 4 lanes sharing lc
// (lg=0..3) -> the running max MUST be reduced across lg (shfl_xor 16,32).
// Row-sum computed by mfma with ones-vector A operand (cross-lane for free).
__global__ __launch_bounds__(128, 4) void attn_kernel(
    const u16* __restrict__ Qt, const u16* __restrict__ Kswz,
    const u16* __restrict__ Vp, u16* __restrict__ O)
{
    __shared__ alignas(16) u16 Kl[64 * 64];
    __shared__ alignas(16) u16 Vl[64 * 64];
    const int bid = blockIdx.x;
    const int qt = 31 - (bid >> 6);      // heavy q-tiles first
    const int bh = bid & 63;
    const int t = threadIdx.x, l = t & 63, w = t >> 6;   // w: 0..1
    const int lg = l >> 4, lc = l & 15;
    const int qb0 = qt * 64 + w * 32;
    const int ntiles = qt + 1;
    const int swz = (lc & 7) << 3;

    bf16x8 qf[2][2];
#pragma unroll
    for (int f = 0; f < 2; ++f)
#pragma unroll
        for (int fk = 0; fk < 2; ++fk)
            qf[f][fk] = *(const bf16x8*)&Qt[((size_t)bh * 2048 + qb0 + 16 * f + lc) * 64 + fk * 32 + lg * 8];

    const bf16x8 ones = { (__bf16)1.f, (__bf16)1.f, (__bf16)1.f, (__bf16)1.f,
                          (__bf16)1.f, (__bf16)1.f, (__bf16)1.f, (__bf16)1.f };

    f32x4 aco[2][4] = {};
    f32x4 aco_sum[2] = {};
    float m[2] = { -1e30f, -1e30f };

    // staging geometry: lane covers (row sr, 16B col scq) of each 1KB chunk
    const int sr = l >> 3;
    const int scq = (l & 7) * 8;
    const u16* gK = Kswz + (size_t)bh * 131072 + scq;
    const u16* gV = Vp + (size_t)bh * 131072 + scq;

    for (int kt = 0; kt < ntiles; ++kt) {
        const int kv0 = kt * 64;
        __syncthreads();                  // readers of previous tile done
#pragma unroll
        for (int j = 0; j < 4; ++j) {
            const int rb = w * 32 + j * 8;
            gload16(gK + (((size_t)(kv0 + rb + sr)) << 6), &Kl[rb * 64]);
            gload16(gV + (size_t)(rb + sr) * 2048 + kv0, &Vl[rb * 64]);
        }
        __syncthreads();                  // vmcnt drained, tile visible

        // S^T = K Q^T
        f32x4 sc[2][4];
        const f32x4 zf = { 0.f, 0.f, 0.f, 0.f };
#pragma unroll
        for (int nb = 0; nb < 4; ++nb) {
            const u16* kr = &Kl[(nb * 16 + lc) * 64];
            bf16x8 kb0 = *(const bf16x8*)&kr[(lg * 8) ^ swz];
            bf16x8 kb1 = *(const bf16x8*)&kr[(32 + lg * 8) ^ swz];
            sc[0][nb] = mfma16(kb0, qf[0][0], zf);
            sc[0][nb] = mfma16(kb1, qf[0][1], sc[0][nb]);
            sc[1][nb] = mfma16(kb0, qf[1][0], zf);
            sc[1][nb] = mfma16(kb1, qf[1][1], sc[1][nb]);
        }

        // mask (diagonal tiles only) + per-q tile max (in-lane tree, then
        // cross-lane reduce over the lg group: lanes ^16 and ^32 share q=lc)
        float pm[2];
#pragma unroll
        for (int f = 0; f < 2; ++f) {
            if (kv0 + 63 > qb0 + 16 * f) {
                const int qq = qb0 + 16 * f + lc;
#pragma unroll
                for (int nb = 0; nb < 4; ++nb) {
                    const int kb = kv0 + nb * 16 + lg * 4;
#pragma unroll
                    for (int jj = 0; jj < 4; ++jj)
                        if (kb + jj > qq) sc[f][nb][jj] = -1e38f;
                }
            }
            float a0 = fmaxf(fmaxf(sc[f][0][0], sc[f][0][1]), fmaxf(sc[f][0][2], sc[f][0][3]));
            float a1 = fmaxf(fmaxf(sc[f][1][0], sc[f][1][1]), fmaxf(sc[f][1][2], sc[f][1][3]));
            float a2 = fmaxf(fmaxf(sc[f][2][0], sc[f][2][1]), fmaxf(sc[f][2][2], sc[f][2][3]));
            float a3 = fmaxf(fmaxf(sc[f][3][0], sc[f][3][1]), fmaxf(sc[f][3][2], sc[f][3][3]));
            float a = fmaxf(fmaxf(a0, a1), fmaxf(a2, a3));
            a = fmaxf(a, __shfl_xor(a, 16));   // reduce over lg bit 0
            a = fmaxf(a, __shfl_xor(a, 32));   // reduce over lg bit 1
            pm[f] = a;
        }

        // defer-max (T13): rescale only when tile-max exceeds m+11 (log2 domain)
        int need = (pm[0] > m[0] + 11.0f) || (pm[1] > m[1] + 11.0f);
        if (__any(need)) {
#pragma unroll
            for (int f = 0; f < 2; ++f) {
                float mn = fmaxf(m[f], pm[f]);
                float scal = exp2f(m[f] - mn);
                m[f] = mn;
                aco_sum[f][0] *= scal;
#pragma unroll
                for (int nb = 0; nb < 4; ++nb) aco[f][nb] *= scal;
            }
        }

        // P = exp2(S - m); pack PV B-frags straight from own registers
        bf16x8 pB[2][2];
#pragma unroll
        for (int f = 0; f < 2; ++f) {
#pragma unroll
            for (int nb = 0; nb < 4; ++nb)
#pragma unroll
                for (int jj = 0; jj < 4; ++jj)
                    sc[f][nb][jj] = exp2f(sc[f][nb][jj] - m[f]);
#pragma unroll
            for (int fk = 0; fk < 2; ++fk) {
                bf16x8 pb;
#pragma unroll
                for (int e = 0; e < 4; ++e) {
                    pb[e]     = (__bf16)sc[f][2 * fk][e];
                    pb[e + 4] = (__bf16)sc[f][2 * fk + 1][e];
                }
                pB[f][fk] = pb;
            }
        }

        // O^T += V^T P^T  (V frag = one b128, slot order baked into Vp layout)
#pragma unroll
        for (int nb = 0; nb < 4; ++nb) {
            const u16* vr = &Vl[(nb * 16 + lc) * 64];
#pragma unroll
            for (int fk = 0; fk < 2; ++fk) {
                bf16x8 va = *(const bf16x8*)&vr[(fk * 32 + lg * 8) ^ swz];
                aco[0][nb] = mfma16(va, pB[0][fk], aco[0][nb]);
                aco[1][nb] = mfma16(va, pB[1][fk], aco[1][nb]);
            }
        }
        // row-sums via ones-MFMA
#pragma unroll
        for (int f = 0; f < 2; ++f) {
            aco_sum[f] = mfma16(ones, pB[f][0], aco_sum[f]);
            aco_sum[f] = mfma16(ones, pB[f][1], aco_sum[f]);
        }
    }

    const int b = bh >> 4, h = bh & 15;
#pragma unroll
    for (int f = 0; f < 2; ++f) {
        float rinv = 1.0f / aco_sum[f][0];
        size_t row = (size_t)b * 2048 + qb0 + 16 * f + lc;
#pragma unroll
        for (int nb = 0; nb < 4; ++nb) {
            u16x4 pk;
#pragma unroll
            for (int jj = 0; jj < 4; ++jj) pk[jj] = f2bf(aco[f][nb][jj] * rinv);
            *(u16x4*)&O[row * 1024 + h * 64 + nb * 16 + lg * 4] = pk;
        }
    }
}

// ---------------- launch ----------------
extern "C" void kernel_launch(void* const* d_in, const int* in_sizes, int n_in,
                              void* d_out, int out_size, void* d_ws, size_t ws_size,
                              hipStream_t stream) {
    const float* x    = (const float*)d_in[0];
    const int*   pos  = (const int*)d_in[1];
    const float* wqkv = (const float*)d_in[2];
    const float* wout = (const float*)d_in[3];
    float* out = (float*)d_out;
    char* ws = (char*)d_ws;

    // workspace layout (bytes)
    u16*    x_bf    = (u16*)(ws);                    // 16,777,216
    u16*    wqkv_bf = (u16*)(ws + 16777216);         //  6,291,456
    u16*    wout_bf = (u16*)(ws + 23068672);         //  2,097,152
    float2* tbl     = (float2*)(ws + 25165824);      //    524,288
    u16*    Qt      = (u16*)(ws + 25690112);         // 16,777,216
    u16*    Kt      = (u16*)(ws + 42467328);         // 16,777,216 (swizzled)
    u16*    VTt     = (u16*)(ws + 59244544);         // 16,777,216 (permuted)
    u16*    O       = (u16*)(ws + 76021760);         // 16,777,216 -> end 92,798,976
    if (ws_size < 92798976u) return;  // loud failure (output stays poisoned)

    cvt_bf16_kernel<<<8192, 256, 0, stream>>>(x, x_bf, 2097152);
    cvt_bf16_kernel<<<3072, 256, 0, stream>>>(wqkv, wqkv_bf, 786432);
    cvt_bf16_kernel<<<1024, 256, 0, stream>>>(wout, wout_bf, 262144);
    rope_tbl_kernel<<<256, 256, 0, stream>>>(pos, tbl);

    dim3 g1(24, 64);   // N=3072/128, M=8192/128
    gemm_bt<1><<<g1, 256, 0, stream>>>(x_bf, wqkv_bf, nullptr, 0, Qt, Kt, VTt, tbl);

    attn_kernel<<<2048, 128, 0, stream>>>(Qt, Kt, VTt, O);

    dim3 g2(8, 64);    // N=1024/128
    gemm_bt<0><<<g2, 256, 0, stream>>>(O, wout_bf, out, 1024, nullptr, nullptr, nullptr, nullptr);
}

// Round 6
// 309.975 us; speedup vs baseline: 1.0342x; 1.0342x over previous
//
#include <hip/hip_runtime.h>

typedef unsigned short u16;
typedef __attribute__((ext_vector_type(4))) float f32x4;
typedef __attribute__((ext_vector_type(8))) __bf16 bf16x8;
typedef __attribute__((ext_vector_type(8))) short short8;
typedef __attribute__((ext_vector_type(4))) u16 u16x4;

__device__ __forceinline__ u16 f2bf(float f) {
    union { float f; unsigned u; } v; v.f = f;
    unsigned r = v.u + 0x7fffu + ((v.u >> 16) & 1u);
    return (u16)(r >> 16);
}

__device__ __forceinline__ f32x4 mfma16(bf16x8 a, bf16x8 b, f32x4 c) {
    return __builtin_amdgcn_mfma_f32_16x16x32_bf16(a, b, c, 0, 0, 0);
}

__device__ __forceinline__ void gload16(const u16* g, u16* lds) {
    __builtin_amdgcn_global_load_lds(
        (const __attribute__((address_space(1))) void*)g,
        (__attribute__((address_space(3))) void*)lds, 16, 0, 0);
}

// ---------------- f32 -> bf16 conversion ----------------
__global__ void cvt_bf16_kernel(const float* __restrict__ src, u16* __restrict__ dst, int n4) {
    int i = blockIdx.x * blockDim.x + threadIdx.x;
    if (i >= n4) return;
    float4 v = ((const float4*)src)[i];
    u16x4 o = { f2bf(v.x), f2bf(v.y), f2bf(v.z), f2bf(v.w) };
    *(u16x4*)&dst[i * 4] = o;
}

// ---------------- RoPE cos/sin table [2048][32] ----------------
__global__ void rope_tbl_kernel(const int* __restrict__ pos, float2* __restrict__ tbl) {
    int i = blockIdx.x * blockDim.x + threadIdx.x;   // 65536
    int s = i >> 5, p = i & 31;
    float inv = powf(10000.0f, -(float)p / 32.0f);
    float a = (float)pos[s] * inv;
    float sn, cs;
    sincosf(a, &sn, &cs);
    tbl[i] = make_float2(cs, sn);
}

// ---------------- GEMM C = A @ B^T  (m97 structure, 128x128 tile, BK=32) ------
// MODE 0: C[row][N] f32 output.
// MODE 1: QKV epilogue: RoPE + split into
//   Q[bh][s][64]  (pre-scaled by 1/8*log2e, attn works in exp2 domain)
//   Kswz[bh][s][d ^ ((s&7)<<3)]                     (XOR-swizzled for LDS)
//   Vp[bh][d][tile][p ^ ((d&7)<<3)] where p encodes the MFMA k-slot order:
//     p = 32*(r>>5) + 8*((r>>2)&3) + 4*((r>>4)&1) + (r&3),  r = kv & 63
template<int MODE>
__global__ __launch_bounds__(256) void gemm_bt(
    const u16* __restrict__ A, const u16* __restrict__ B,
    float* __restrict__ C, int N,
    u16* __restrict__ Qt, u16* __restrict__ Ktn, u16* __restrict__ VTt,
    const float2* __restrict__ tbl)
{
    __shared__ alignas(16) u16 As[128 * 32];
    __shared__ alignas(16) u16 Bs[128 * 32];
    const int t = threadIdx.x;
    const int l = t & 63, w = t >> 6;
    const int lg = l >> 4, lc = l & 15;
    const int wr = w >> 1, wc = w & 1;
    const int brow = blockIdx.y * 128, bcol = blockIdx.x * 128;
    const int sr = w * 16 + (l >> 2), sc = (l & 3) * 8;
    const u16* ga = A + (size_t)(brow + sr) * 1024 + sc;
    const u16* gb = B + (size_t)(bcol + sr) * 1024 + sc;
    u16* la = &As[w * 512];
    u16* lb = &Bs[w * 512];
    f32x4 acc[4][4] = {};

    for (int kt = 0; kt < 1024; kt += 32) {
        __syncthreads();
        gload16(ga + kt, la);
        gload16(ga + 64 * 1024 + kt, la + 2048);
        gload16(gb + kt, lb);
        gload16(gb + 64 * 1024 + kt, lb + 2048);
        __syncthreads();
        bf16x8 af[4], bfr[4];
#pragma unroll
        for (int i = 0; i < 4; ++i)
            af[i] = *(const bf16x8*)&As[(wr * 64 + i * 16 + lc) * 32 + lg * 8];
#pragma unroll
        for (int j = 0; j < 4; ++j)
            bfr[j] = *(const bf16x8*)&Bs[(wc * 64 + j * 16 + lc) * 32 + lg * 8];
#pragma unroll
        for (int i = 0; i < 4; ++i)
#pragma unroll
            for (int j = 0; j < 4; ++j)
                acc[i][j] = mfma16(af[i], bfr[j], acc[i][j]);
    }

    if (MODE == 0) {
#pragma unroll
        for (int i = 0; i < 4; ++i) {
            int row = brow + wr * 64 + i * 16 + lg * 4;
#pragma unroll
            for (int j = 0; j < 4; ++j) {
                int col = bcol + wc * 64 + j * 16 + lc;
#pragma unroll
                for (int jj = 0; jj < 4; ++jj)
                    C[(size_t)(row + jj) * N + col] = acc[i][j][jj];
            }
        }
    } else {
        const int b = brow >> 11;
#pragma unroll
        for (int i = 0; i < 4; ++i) {
            int s0 = (brow & 2047) + wr * 64 + i * 16 + lg * 4;
#pragma unroll
            for (int j = 0; j < 4; ++j) {
                int e0 = bcol + wc * 64 + j * 16;     // wave-uniform
                int region = e0 >> 10;                // 0=q 1=k 2=v
                int er = e0 & 1023;
                int h = er >> 6;                      // wave-uniform
                int d = (er & 63) + lc;               // per-lane
                size_t bh = (size_t)(b * 16 + h);
                if (region <= 1) {
                    int p = d >> 1;
                    float sgn = (d & 1) ? 1.0f : -1.0f;   // even: -sin, odd: +sin
                    u16* dst = (region == 0) ? Qt : Ktn;
                    float mul = (region == 0) ? 0.18033688011112043f : 1.0f;
#pragma unroll
                    for (int jj = 0; jj < 4; ++jj) {
                        float v = acc[i][j][jj];
                        float pr = __shfl_xor(v, 1);
                        float2 cs = tbl[(size_t)(s0 + jj) * 32 + p];
                        float o = (v * cs.x + pr * cs.y * sgn) * mul;
                        int s = s0 + jj;
                        int dd = (region == 0) ? d : (d ^ ((s & 7) << 3));
                        dst[((size_t)bh * 2048 + s) * 64 + dd] = f2bf(o);
                    }
                } else {
                    // V: permuted + swizzled layout for direct b128 PV A-frag reads
                    int tile = s0 >> 6, r = s0 & 63;
                    int p0 = ((r >> 5) << 5) + (((r >> 2) & 3) << 3) + (((r >> 4) & 1) << 2);
                    int idx = (tile << 6) + (p0 ^ ((d & 7) << 3));
                    u16x4 pk;
#pragma unroll
                    for (int jj = 0; jj < 4; ++jj) pk[jj] = f2bf(acc[i][j][jj]);
                    *(u16x4*)&VTt[((size_t)bh * 64 + d) * 2048 + idx] = pk;
                }
            }
        }
    }
}

// ---------------- causal flash attention (swapped-operand, 2-phase pipeline) --
// grid: 1024 blocks = 16 q-tiles x 64 bh -> exactly 4 blocks/CU, all resident.
// Block: 4 waves x 32 q (2 frags of 16); KVBLK=64; double-buffered LDS.
// T3 minimum-2-phase: stage(buf^1, t+1) issued BEFORE compute(buf), single
// __syncthreads per tile (its implicit vmcnt(0) drains the prefetch after
// compute -> HBM/L2 latency hidden under the MFMA/VALU phase).
// S^T = mfma(K,Q): lane(lg,lc) elem jj -> k=kv0+nb*16+4lg+jj, q=qb0+16f+lc.
// Running max reduced across the lg group (shfl_xor 16,32); row-sum via
// ones-vector MFMA (cross-lane for free).
__global__ __launch_bounds__(256, 4) void attn_kernel(
    const u16* __restrict__ Qt, const u16* __restrict__ Kswz,
    const u16* __restrict__ Vp, u16* __restrict__ O)
{
    __shared__ alignas(16) u16 Kl[2][64 * 64];
    __shared__ alignas(16) u16 Vl[2][64 * 64];
    const int bid = blockIdx.x;
    const int qt = 15 - (bid >> 6);      // heavy q-tiles first
    const int bh = bid & 63;
    const int t = threadIdx.x, l = t & 63, w = t >> 6;   // w: 0..3
    const int lg = l >> 4, lc = l & 15;
    const int qb0 = qt * 128 + w * 32;
    const int ntiles = 2 * qt + 2;
    const int swz = (lc & 7) << 3;

    bf16x8 qf[2][2];
#pragma unroll
    for (int f = 0; f < 2; ++f)
#pragma unroll
        for (int fk = 0; fk < 2; ++fk)
            qf[f][fk] = *(const bf16x8*)&Qt[((size_t)bh * 2048 + qb0 + 16 * f + lc) * 64 + fk * 32 + lg * 8];

    const bf16x8 ones = { (__bf16)1.f, (__bf16)1.f, (__bf16)1.f, (__bf16)1.f,
                          (__bf16)1.f, (__bf16)1.f, (__bf16)1.f, (__bf16)1.f };

    f32x4 aco[2][4] = {};
    f32x4 aco_sum[2] = {};
    float m[2] = { -1e30f, -1e30f };

    // staging: 256 threads cover a 64x64 u16 tile in 2 rounds of 16B chunks
    const int srow = t >> 3;            // 0..31
    const int scol = (t & 7) * 8;       // u16 col offset
    const u16* gK = Kswz + (size_t)bh * 131072;
    const u16* gV = Vp + (size_t)bh * 131072;

    auto stage = [&](int buf, int kv0) {
        gload16(gK + ((size_t)(kv0 + srow) << 6) + scol,      &Kl[buf][srow * 64 + scol]);
        gload16(gK + ((size_t)(kv0 + srow + 32) << 6) + scol, &Kl[buf][(srow + 32) * 64 + scol]);
        gload16(gV + (size_t)srow * 2048 + kv0 + scol,        &Vl[buf][srow * 64 + scol]);
        gload16(gV + (size_t)(srow + 32) * 2048 + kv0 + scol, &Vl[buf][(srow + 32) * 64 + scol]);
    };

    stage(0, 0);
    __syncthreads();                     // prologue drain (vmcnt(0) + barrier)
    int cur = 0;

    for (int kt = 0; kt < ntiles; ++kt) {
        const int kv0 = kt * 64;
        if (kt + 1 < ntiles) stage(cur ^ 1, kv0 + 64);   // prefetch under compute

        // single act: for this geometry act0==act1 provably (kv0-qb0 ≡ 0/32 mod 64)
        if (kv0 <= qb0 + 31) {
            const u16* Kc = Kl[cur];
            const u16* Vc = Vl[cur];

            // S^T = K Q^T
            f32x4 sc[2][4];
            const f32x4 zf = { 0.f, 0.f, 0.f, 0.f };
#pragma unroll
            for (int nb = 0; nb < 4; ++nb) {
                const u16* kr = &Kc[(nb * 16 + lc) * 64];
                bf16x8 kb0 = *(const bf16x8*)&kr[(lg * 8) ^ swz];
                bf16x8 kb1 = *(const bf16x8*)&kr[(32 + lg * 8) ^ swz];
                sc[0][nb] = mfma16(kb0, qf[0][0], zf);
                sc[0][nb] = mfma16(kb1, qf[0][1], sc[0][nb]);
                sc[1][nb] = mfma16(kb0, qf[1][0], zf);
                sc[1][nb] = mfma16(kb1, qf[1][1], sc[1][nb]);
            }

            // mask (diagonal tiles only) + per-q tile max (in-lane tree, then
            // cross-lane reduce over lg group: lanes ^16 and ^32 share q=lc)
            float pm[2];
#pragma unroll
            for (int f = 0; f < 2; ++f) {
                if (kv0 + 63 > qb0 + 16 * f) {
                    const int qq = qb0 + 16 * f + lc;
#pragma unroll
                    for (int nb = 0; nb < 4; ++nb) {
                        const int kb = kv0 + nb * 16 + lg * 4;
#pragma unroll
                        for (int jj = 0; jj < 4; ++jj)
                            if (kb + jj > qq) sc[f][nb][jj] = -1e38f;
                    }
                }
                float a0 = fmaxf(fmaxf(sc[f][0][0], sc[f][0][1]), fmaxf(sc[f][0][2], sc[f][0][3]));
                float a1 = fmaxf(fmaxf(sc[f][1][0], sc[f][1][1]), fmaxf(sc[f][1][2], sc[f][1][3]));
                float a2 = fmaxf(fmaxf(sc[f][2][0], sc[f][2][1]), fmaxf(sc[f][2][2], sc[f][2][3]));
                float a3 = fmaxf(fmaxf(sc[f][3][0], sc[f][3][1]), fmaxf(sc[f][3][2], sc[f][3][3]));
                float a = fmaxf(fmaxf(a0, a1), fmaxf(a2, a3));
                a = fmaxf(a, __shfl_xor(a, 16));
                a = fmaxf(a, __shfl_xor(a, 32));
                pm[f] = a;
            }

            // defer-max (T13): rescale only when tile-max exceeds m+11 (log2 dom)
            int need = (pm[0] > m[0] + 11.0f) || (pm[1] > m[1] + 11.0f);
            if (__any(need)) {
#pragma unroll
                for (int f = 0; f < 2; ++f) {
                    float mn = fmaxf(m[f], pm[f]);
                    float scal = exp2f(m[f] - mn);
                    m[f] = mn;
                    aco_sum[f][0] *= scal;
#pragma unroll
                    for (int nb = 0; nb < 4; ++nb) aco[f][nb] *= scal;
                }
            }

            // P = exp2(S - m); pack PV B-frags straight from own registers
            bf16x8 pB[2][2];
#pragma unroll
            for (int f = 0; f < 2; ++f) {
#pragma unroll
                for (int nb = 0; nb < 4; ++nb)
#pragma unroll
                    for (int jj = 0; jj < 4; ++jj)
                        sc[f][nb][jj] = exp2f(sc[f][nb][jj] - m[f]);
#pragma unroll
                for (int fk = 0; fk < 2; ++fk) {
                    bf16x8 pb;
#pragma unroll
                    for (int e = 0; e < 4; ++e) {
                        pb[e]     = (__bf16)sc[f][2 * fk][e];
                        pb[e + 4] = (__bf16)sc[f][2 * fk + 1][e];
                    }
                    pB[f][fk] = pb;
                }
            }

            // O^T += V^T P^T  (V frag = one b128, slot order baked into Vp)
#pragma unroll
            for (int nb = 0; nb < 4; ++nb) {
                const u16* vr = &Vc[(nb * 16 + lc) * 64];
#pragma unroll
                for (int fk = 0; fk < 2; ++fk) {
                    bf16x8 va = *(const bf16x8*)&vr[(fk * 32 + lg * 8) ^ swz];
                    aco[0][nb] = mfma16(va, pB[0][fk], aco[0][nb]);
                    aco[1][nb] = mfma16(va, pB[1][fk], aco[1][nb]);
                }
            }
            // row-sums via ones-MFMA
#pragma unroll
            for (int f = 0; f < 2; ++f) {
                aco_sum[f] = mfma16(ones, pB[f][0], aco_sum[f]);
                aco_sum[f] = mfma16(ones, pB[f][1], aco_sum[f]);
            }
        }

        __syncthreads();                 // drains prefetch vmcnt + barriers
        cur ^= 1;
    }

    const int b = bh >> 4, h = bh & 15;
#pragma unroll
    for (int f = 0; f < 2; ++f) {
        float rinv = 1.0f / aco_sum[f][0];
        size_t row = (size_t)b * 2048 + qb0 + 16 * f + lc;
#pragma unroll
        for (int nb = 0; nb < 4; ++nb) {
            u16x4 pk;
#pragma unroll
            for (int jj = 0; jj < 4; ++jj) pk[jj] = f2bf(aco[f][nb][jj] * rinv);
            *(u16x4*)&O[row * 1024 + h * 64 + nb * 16 + lg * 4] = pk;
        }
    }
}

// ---------------- launch ----------------
extern "C" void kernel_launch(void* const* d_in, const int* in_sizes, int n_in,
                              void* d_out, int out_size, void* d_ws, size_t ws_size,
                              hipStream_t stream) {
    const float* x    = (const float*)d_in[0];
    const int*   pos  = (const int*)d_in[1];
    const float* wqkv = (const float*)d_in[2];
    const float* wout = (const float*)d_in[3];
    float* out = (float*)d_out;
    char* ws = (char*)d_ws;

    // workspace layout (bytes)
    u16*    x_bf    = (u16*)(ws);                    // 16,777,216
    u16*    wqkv_bf = (u16*)(ws + 16777216);         //  6,291,456
    u16*    wout_bf = (u16*)(ws + 23068672);         //  2,097,152
    float2* tbl     = (float2*)(ws + 25165824);      //    524,288
    u16*    Qt      = (u16*)(ws + 25690112);         // 16,777,216
    u16*    Kt      = (u16*)(ws + 42467328);         // 16,777,216 (swizzled)
    u16*    VTt     = (u16*)(ws + 59244544);         // 16,777,216 (permuted)
    u16*    O       = (u16*)(ws + 76021760);         // 16,777,216 -> end 92,798,976
    if (ws_size < 92798976u) return;  // loud failure (output stays poisoned)

    cvt_bf16_kernel<<<8192, 256, 0, stream>>>(x, x_bf, 2097152);
    cvt_bf16_kernel<<<3072, 256, 0, stream>>>(wqkv, wqkv_bf, 786432);
    cvt_bf16_kernel<<<1024, 256, 0, stream>>>(wout, wout_bf, 262144);
    rope_tbl_kernel<<<256, 256, 0, stream>>>(pos, tbl);

    dim3 g1(24, 64);   // N=3072/128, M=8192/128
    gemm_bt<1><<<g1, 256, 0, stream>>>(x_bf, wqkv_bf, nullptr, 0, Qt, Kt, VTt, tbl);

    attn_kernel<<<1024, 256, 0, stream>>>(Qt, Kt, VTt, O);

    dim3 g2(8, 64);    // N=1024/128
    gemm_bt<0><<<g2, 256, 0, stream>>>(O, wout_bf, out, 1024, nullptr, nullptr, nullptr, nullptr);
}

// Round 8
// 293.712 us; speedup vs baseline: 1.0915x; 1.0554x over previous
//
#include <hip/hip_runtime.h>

typedef unsigned short u16;
typedef __attribute__((ext_vector_type(4))) float f32x4;
typedef __attribute__((ext_vector_type(8))) __bf16 bf16x8;
typedef __attribute__((ext_vector_type(8))) short short8;
typedef __attribute__((ext_vector_type(4))) u16 u16x4;

__device__ __forceinline__ u16 f2bf(float f) {
    union { float f; unsigned u; } v; v.f = f;
    unsigned r = v.u + 0x7fffu + ((v.u >> 16) & 1u);
    return (u16)(r >> 16);
}

__device__ __forceinline__ f32x4 mfma16(bf16x8 a, bf16x8 b, f32x4 c) {
    return __builtin_amdgcn_mfma_f32_16x16x32_bf16(a, b, c, 0, 0, 0);
}

__device__ __forceinline__ void gload16(const u16* g, u16* lds) {
    __builtin_amdgcn_global_load_lds(
        (const __attribute__((address_space(1))) void*)g,
        (__attribute__((address_space(3))) void*)lds, 16, 0, 0);
}

// ---------------- f32 -> bf16 conversion ----------------
__global__ void cvt_bf16_kernel(const float* __restrict__ src, u16* __restrict__ dst, int n4) {
    int i = blockIdx.x * blockDim.x + threadIdx.x;
    if (i >= n4) return;
    float4 v = ((const float4*)src)[i];
    u16x4 o = { f2bf(v.x), f2bf(v.y), f2bf(v.z), f2bf(v.w) };
    *(u16x4*)&dst[i * 4] = o;
}

// ---------------- RoPE cos/sin table [2048][32] ----------------
__global__ void rope_tbl_kernel(const int* __restrict__ pos, float2* __restrict__ tbl) {
    int i = blockIdx.x * blockDim.x + threadIdx.x;   // 65536
    int s = i >> 5, p = i & 31;
    float inv = powf(10000.0f, -(float)p / 32.0f);
    float a = (float)pos[s] * inv;
    float sn, cs;
    sincosf(a, &sn, &cs);
    tbl[i] = make_float2(cs, sn);
}

// ---------------- GEMM C = A @ B^T  (m97 structure, 128x128 tile, BK=32) ------
// MODE 0: C[row][N] f32 output.
// MODE 1: QKV epilogue: RoPE + split into
//   Q[bh][s][64]  (pre-scaled by 1/8*log2e, attn works in exp2 domain)
//   Kswz[bh][s][d ^ ((s&7)<<3)]          (XOR-swizzled for conflict-free LDS)
//   Vg[bh][tile64][nb][fk][lane][8]      (fragment-major gather: PV A-frag is
//     one coalesced b128/lane). For kv r = s&63: fk=r>>5, lg=(r>>2)&3,
//     e = 4*((r>>4)&1) + (r&3); nb = d>>4, lc = d&15, lane = lg*16+lc.
//     This inverts the MFMA k-slot map kappa = 32fk + 16(e>>2) + 4lg + (e&3).
template<int MODE>
__global__ __launch_bounds__(256) void gemm_bt(
    const u16* __restrict__ A, const u16* __restrict__ B,
    float* __restrict__ C, int N,
    u16* __restrict__ Qt, u16* __restrict__ Ktn, u16* __restrict__ VTt,
    const float2* __restrict__ tbl)
{
    __shared__ alignas(16) u16 As[128 * 32];
    __shared__ alignas(16) u16 Bs[128 * 32];
    const int t = threadIdx.x;
    const int l = t & 63, w = t >> 6;
    const int lg = l >> 4, lc = l & 15;
    const int wr = w >> 1, wc = w & 1;
    const int brow = blockIdx.y * 128, bcol = blockIdx.x * 128;
    const int sr = w * 16 + (l >> 2), sc = (l & 3) * 8;
    const u16* ga = A + (size_t)(brow + sr) * 1024 + sc;
    const u16* gb = B + (size_t)(bcol + sr) * 1024 + sc;
    u16* la = &As[w * 512];
    u16* lb = &Bs[w * 512];
    f32x4 acc[4][4] = {};

    for (int kt = 0; kt < 1024; kt += 32) {
        __syncthreads();
        gload16(ga + kt, la);
        gload16(ga + 64 * 1024 + kt, la + 2048);
        gload16(gb + kt, lb);
        gload16(gb + 64 * 1024 + kt, lb + 2048);
        __syncthreads();
        bf16x8 af[4], bfr[4];
#pragma unroll
        for (int i = 0; i < 4; ++i)
            af[i] = *(const bf16x8*)&As[(wr * 64 + i * 16 + lc) * 32 + lg * 8];
#pragma unroll
        for (int j = 0; j < 4; ++j)
            bfr[j] = *(const bf16x8*)&Bs[(wc * 64 + j * 16 + lc) * 32 + lg * 8];
#pragma unroll
        for (int i = 0; i < 4; ++i)
#pragma unroll
            for (int j = 0; j < 4; ++j)
                acc[i][j] = mfma16(af[i], bfr[j], acc[i][j]);
    }

    if (MODE == 0) {
#pragma unroll
        for (int i = 0; i < 4; ++i) {
            int row = brow + wr * 64 + i * 16 + lg * 4;
#pragma unroll
            for (int j = 0; j < 4; ++j) {
                int col = bcol + wc * 64 + j * 16 + lc;
#pragma unroll
                for (int jj = 0; jj < 4; ++jj)
                    C[(size_t)(row + jj) * N + col] = acc[i][j][jj];
            }
        }
    } else {
        const int b = brow >> 11;
#pragma unroll
        for (int i = 0; i < 4; ++i) {
            int s0 = (brow & 2047) + wr * 64 + i * 16 + lg * 4;
#pragma unroll
            for (int j = 0; j < 4; ++j) {
                int e0 = bcol + wc * 64 + j * 16;     // wave-uniform
                int region = e0 >> 10;                // 0=q 1=k 2=v
                int er = e0 & 1023;
                int h = er >> 6;                      // wave-uniform
                int d = (er & 63) + lc;               // per-lane
                size_t bh = (size_t)(b * 16 + h);
                if (region <= 1) {
                    int p = d >> 1;
                    float sgn = (d & 1) ? 1.0f : -1.0f;   // even: -sin, odd: +sin
                    u16* dst = (region == 0) ? Qt : Ktn;
                    float mul = (region == 0) ? 0.18033688011112043f : 1.0f;
#pragma unroll
                    for (int jj = 0; jj < 4; ++jj) {
                        float v = acc[i][j][jj];
                        float pr = __shfl_xor(v, 1);
                        float2 cs = tbl[(size_t)(s0 + jj) * 32 + p];
                        float o = (v * cs.x + pr * cs.y * sgn) * mul;
                        int s = s0 + jj;
                        int dd = (region == 0) ? d : (d ^ ((s & 7) << 3));
                        dst[((size_t)bh * 2048 + s) * 64 + dd] = f2bf(o);
                    }
                } else {
                    // V fragment-major gather layout (s0 is a multiple of 4, so
                    // jj 0..3 land in contiguous e slots)
                    int tile = s0 >> 6, r = s0 & 63;
                    int fk = r >> 5, lgg = (r >> 2) & 3, eb = ((r >> 4) & 1) * 4;
                    size_t off = bh * 131072 + (size_t)tile * 4096 +
                                 (size_t)(d >> 4) * 1024 + fk * 512 + lgg * 128 +
                                 (d & 15) * 8 + eb;
                    u16x4 pk;
#pragma unroll
                    for (int jj = 0; jj < 4; ++jj) pk[jj] = f2bf(acc[i][j][jj]);
                    *(u16x4*)&VTt[off] = pk;
                }
            }
        }
    }
}

// ---------------- causal flash attention (swapped-operand, v4) ----------------
// grid: 1024 blocks; Latin-square qt schedule -> every CU's 4 blocks sum to 34
// tiles. Block: 4 waves x 32 q. K staged 128 kv/barrier into dbuf LDS (32 KB),
// computed in two 64-kv subtiles; ONE barrier per 128 kv. V read per-wave
// straight from the gather layout (coalesced b128, no LDS, no barrier dep).
// S^T = mfma(K,Q): lane(lg,lc) elem jj -> k=kvs+nb*16+4lg+jj, q=qb0+16f+lc.
// Running max reduced across the lg group (shfl_xor 16,32); row-sum via
// ones-vector MFMA.
__global__ __launch_bounds__(256, 4) void attn_kernel(
    const u16* __restrict__ Qt, const u16* __restrict__ Kswz,
    const u16* __restrict__ Vg, u16* __restrict__ O)
{
    __shared__ alignas(16) u16 Kl[2][128 * 64];   // 32 KB
    const int bid = blockIdx.x;
    const int rr_ = bid >> 8, aa_ = (bid >> 6) & 3;
    const int bh = bid & 63;
    const int qt = (rr_ == 0) ? 15 - 2 * aa_
                 : (rr_ == 1) ? 8 + 2 * aa_
                 : (rr_ == 2) ? 7 - 2 * aa_
                              : 2 * aa_;
    const int t = threadIdx.x, l = t & 63, w = t >> 6;   // w: 0..3
    const int lg = l >> 4, lc = l & 15;
    const int qb0 = qt * 128 + w * 32;
    const int ntiles = qt + 1;                // 128-kv tiles
    const int swz = (lc & 7) << 3;

    bf16x8 qf[2][2];
#pragma unroll
    for (int f = 0; f < 2; ++f)
#pragma unroll
        for (int fk = 0; fk < 2; ++fk)
            qf[f][fk] = *(const bf16x8*)&Qt[((size_t)bh * 2048 + qb0 + 16 * f + lc) * 64 + fk * 32 + lg * 8];

    const bf16x8 ones = { (__bf16)1.f, (__bf16)1.f, (__bf16)1.f, (__bf16)1.f,
                          (__bf16)1.f, (__bf16)1.f, (__bf16)1.f, (__bf16)1.f };

    f32x4 aco[2][4] = {};
    f32x4 aco_sum[2] = {};
    float m[2] = { -1e30f, -1e30f };

    // K staging: 256 threads x 4 rounds of 16B cover 128x64 u16
    const int srow = t >> 3;            // 0..31
    const int scol = (t & 7) * 8;
    const u16* gK = Kswz + (size_t)bh * 131072;
    const u16* gV = Vg + (size_t)bh * 131072 + l * 8;

    auto stageK = [&](int buf, int kv0) {
#pragma unroll
        for (int c = 0; c < 4; ++c)
            gload16(gK + ((size_t)(kv0 + srow + 32 * c) << 6) + scol,
                    &Kl[buf][(srow + 32 * c) * 64 + scol]);
    };

    stageK(0, 0);
    __syncthreads();                     // prologue drain
    int cur = 0;

    for (int kt = 0; kt < ntiles; ++kt) {
        const int kv0 = kt * 128;
        if (kt + 1 < ntiles) stageK(cur ^ 1, kv0 + 128);   // prefetch, 2-subtile window

#pragma unroll
        for (int sub = 0; sub < 2; ++sub) {
            const int kvs = kv0 + sub * 64;
            if (kvs <= qb0 + 31) {
                const u16* Kc = &Kl[cur][(sub << 6) * 64];

                // S^T = K Q^T
                f32x4 sc[2][4];
                const f32x4 zf = { 0.f, 0.f, 0.f, 0.f };
                __builtin_amdgcn_s_setprio(1);
#pragma unroll
                for (int nb = 0; nb < 4; ++nb) {
                    const u16* kr = &Kc[(nb * 16 + lc) * 64];
                    bf16x8 kb0 = *(const bf16x8*)&kr[(lg * 8) ^ swz];
                    bf16x8 kb1 = *(const bf16x8*)&kr[(32 + lg * 8) ^ swz];
                    sc[0][nb] = mfma16(kb0, qf[0][0], zf);
                    sc[0][nb] = mfma16(kb1, qf[0][1], sc[0][nb]);
                    sc[1][nb] = mfma16(kb0, qf[1][0], zf);
                    sc[1][nb] = mfma16(kb1, qf[1][1], sc[1][nb]);
                }
                __builtin_amdgcn_s_setprio(0);

                // mask (diagonal subtiles) + per-q tile max; reduce across lg
                float pm[2];
#pragma unroll
                for (int f = 0; f < 2; ++f) {
                    if (kvs + 63 > qb0 + 16 * f) {
                        const int qq = qb0 + 16 * f + lc;
#pragma unroll
                        for (int nb = 0; nb < 4; ++nb) {
                            const int kb = kvs + nb * 16 + lg * 4;
#pragma unroll
                            for (int jj = 0; jj < 4; ++jj)
                                if (kb + jj > qq) sc[f][nb][jj] = -1e38f;
                        }
                    }
                    float a0 = fmaxf(fmaxf(sc[f][0][0], sc[f][0][1]), fmaxf(sc[f][0][2], sc[f][0][3]));
                    float a1 = fmaxf(fmaxf(sc[f][1][0], sc[f][1][1]), fmaxf(sc[f][1][2], sc[f][1][3]));
                    float a2 = fmaxf(fmaxf(sc[f][2][0], sc[f][2][1]), fmaxf(sc[f][2][2], sc[f][2][3]));
                    float a3 = fmaxf(fmaxf(sc[f][3][0], sc[f][3][1]), fmaxf(sc[f][3][2], sc[f][3][3]));
                    float a = fmaxf(fmaxf(a0, a1), fmaxf(a2, a3));
                    a = fmaxf(a, __shfl_xor(a, 16));
                    a = fmaxf(a, __shfl_xor(a, 32));
                    pm[f] = a;
                }

                // defer-max (T13)
                int need = (pm[0] > m[0] + 11.0f) || (pm[1] > m[1] + 11.0f);
                if (__any(need)) {
#pragma unroll
                    for (int f = 0; f < 2; ++f) {
                        float mn = fmaxf(m[f], pm[f]);
                        float scal = exp2f(m[f] - mn);
                        m[f] = mn;
                        aco_sum[f][0] *= scal;
#pragma unroll
                        for (int nb = 0; nb < 4; ++nb) aco[f][nb] *= scal;
                    }
                }

                // P = exp2(S - m); pack PV B-frags from own registers
                bf16x8 pB[2][2];
#pragma unroll
                for (int f = 0; f < 2; ++f) {
#pragma unroll
                    for (int nb = 0; nb < 4; ++nb)
#pragma unroll
                        for (int jj = 0; jj < 4; ++jj)
                            sc[f][nb][jj] = exp2f(sc[f][nb][jj] - m[f]);
#pragma unroll
                    for (int fk = 0; fk < 2; ++fk) {
                        bf16x8 pb;
#pragma unroll
                        for (int e = 0; e < 4; ++e) {
                            pb[e]     = (__bf16)sc[f][2 * fk][e];
                            pb[e + 4] = (__bf16)sc[f][2 * fk + 1][e];
                        }
                        pB[f][fk] = pb;
                    }
                }

                // V fragments: coalesced per-wave b128 from gather layout
                const u16* vt = gV + ((size_t)(2 * kt + sub) << 12);
                bf16x8 va[4][2];
#pragma unroll
                for (int nb = 0; nb < 4; ++nb)
#pragma unroll
                    for (int fk = 0; fk < 2; ++fk)
                        va[nb][fk] = *(const bf16x8*)(vt + nb * 1024 + fk * 512);

                __builtin_amdgcn_s_setprio(1);
#pragma unroll
                for (int nb = 0; nb < 4; ++nb)
#pragma unroll
                    for (int fk = 0; fk < 2; ++fk) {
                        aco[0][nb] = mfma16(va[nb][fk], pB[0][fk], aco[0][nb]);
                        aco[1][nb] = mfma16(va[nb][fk], pB[1][fk], aco[1][nb]);
                    }
#pragma unroll
                for (int f = 0; f < 2; ++f) {
                    aco_sum[f] = mfma16(ones, pB[f][0], aco_sum[f]);
                    aco_sum[f] = mfma16(ones, pB[f][1], aco_sum[f]);
                }
                __builtin_amdgcn_s_setprio(0);
            }
        }

        __syncthreads();                 // drains prefetch; one barrier / 128 kv
        cur ^= 1;
    }

    const int b = bh >> 4, h = bh & 15;
#pragma unroll
    for (int f = 0; f < 2; ++f) {
        float rinv = 1.0f / aco_sum[f][0];
        size_t row = (size_t)b * 2048 + qb0 + 16 * f + lc;
#pragma unroll
        for (int nb = 0; nb < 4; ++nb) {
            u16x4 pk;
#pragma unroll
            for (int jj = 0; jj < 4; ++jj) pk[jj] = f2bf(aco[f][nb][jj] * rinv);
            *(u16x4*)&O[row * 1024 + h * 64 + nb * 16 + lg * 4] = pk;
        }
    }
}

// ---------------- launch ----------------
extern "C" void kernel_launch(void* const* d_in, const int* in_sizes, int n_in,
                              void* d_out, int out_size, void* d_ws, size_t ws_size,
                              hipStream_t stream) {
    const float* x    = (const float*)d_in[0];
    const int*   pos  = (const int*)d_in[1];
    const float* wqkv = (const float*)d_in[2];
    const float* wout = (const float*)d_in[3];
    float* out = (float*)d_out;
    char* ws = (char*)d_ws;

    // workspace layout (bytes)
    u16*    x_bf    = (u16*)(ws);                    // 16,777,216
    u16*    wqkv_bf = (u16*)(ws + 16777216);         //  6,291,456
    u16*    wout_bf = (u16*)(ws + 23068672);         //  2,097,152
    float2* tbl     = (float2*)(ws + 25165824);      //    524,288
    u16*    Qt      = (u16*)(ws + 25690112);         // 16,777,216
    u16*    Kt      = (u16*)(ws + 42467328);         // 16,777,216 (swizzled)
    u16*    VTt     = (u16*)(ws + 59244544);         // 16,777,216 (fragment-major gather)
    u16*    O       = (u16*)(ws + 76021760);         // 16,777,216 -> end 92,798,976
    if (ws_size < 92798976u) return;  // loud failure (output stays poisoned)

    cvt_bf16_kernel<<<8192, 256, 0, stream>>>(x, x_bf, 2097152);
    cvt_bf16_kernel<<<3072, 256, 0, stream>>>(wqkv, wqkv_bf, 786432);
    cvt_bf16_kernel<<<1024, 256, 0, stream>>>(wout, wout_bf, 262144);
    rope_tbl_kernel<<<256, 256, 0, stream>>>(pos, tbl);

    dim3 g1(24, 64);   // N=3072/128, M=8192/128
    gemm_bt<1><<<g1, 256, 0, stream>>>(x_bf, wqkv_bf, nullptr, 0, Qt, Kt, VTt, tbl);

    attn_kernel<<<1024, 256, 0, stream>>>(Qt, Kt, VTt, O);

    dim3 g2(8, 64);    // N=1024/128
    gemm_bt<0><<<g2, 256, 0, stream>>>(O, wout_bf, out, 1024, nullptr, nullptr, nullptr, nullptr);
}